// Round 4
// baseline (2478.157 us; speedup 1.0000x reference)
//
#include <hip/hip_runtime.h>
#include <hip/hip_bf16.h>

#define N_NODES 8192
#define N_EDGES 65536
#define EP (N_EDGES + N_NODES)   // 73728 edges incl self-loops
#define N_GROUPS 64
#define DEGCAP 64
#define EDGE_B 4

typedef __bf16 bf16_t;
typedef bf16_t bf16x8 __attribute__((ext_vector_type(8)));
typedef float  f32x4  __attribute__((ext_vector_type(4)));

__device__ __forceinline__ float lrelu(float v){ return v > 0.f ? v : 0.2f*v; }

__device__ __forceinline__ void gload_lds16(const void* g, void* l){
  typedef __attribute__((address_space(1))) const void gvoid_t;
  typedef __attribute__((address_space(3))) void lvoid_t;
  __builtin_amdgcn_global_load_lds((gvoid_t*)g, (lvoid_t*)l, 16, 0, 0);
}

// bf16-pair pack/unpack (lo -> low 16 bits, hi -> high 16 bits)
__device__ __forceinline__ unsigned pk2(float a, float b){
  __hip_bfloat16 ha = __float2bfloat16(a), hb = __float2bfloat16(b);
  unsigned short ua = *(unsigned short*)&ha, ub = *(unsigned short*)&hb;
  return (unsigned)ua | ((unsigned)ub << 16);
}
__device__ __forceinline__ float bf_lo(unsigned u){ union{unsigned i;float f;}x; x.i = u << 16; return x.f; }
__device__ __forceinline__ float bf_hi(unsigned u){ union{unsigned i;float f;}x; x.i = u & 0xffff0000u; return x.f; }

// ---------------- feature encoding ----------------
__global__ void k_encode_nodes(const float* __restrict__ x, const float* __restrict__ atom_emb,
                               const float* __restrict__ bool_emb, float* __restrict__ h){
  int idx = blockIdx.x*blockDim.x + threadIdx.x;
  if (idx >= N_NODES*74) return;
  int n = idx / 74, c = idx % 74;
  float v;
  if (c < 64)      { int ai = (int)x[n*10+0]; v = atom_emb[ai*64 + c]; }
  else if (c < 72) { v = x[n*10 + 1 + (c-64)]; }
  else             { int bi = (int)x[n*10+9]; v = bool_emb[bi*2 + (c-72)]; }
  h[n*74 + c] = v;
}

// incoming-degree count (real edges only)
__global__ void k_deg(const int* __restrict__ ei, int* __restrict__ deg){
  int e = blockIdx.x*blockDim.x + threadIdx.x;
  if (e >= N_EDGES) return;
  atomicAdd(&deg[ei[N_EDGES + e]], 1);
}

// exclusive scan of (deg[i]+1) over 8192 entries -> rowptr (self-loop slot included)
__global__ __launch_bounds__(1024) void k_scan(const int* __restrict__ deg, int* __restrict__ rowptr){
  __shared__ int buf[1024];
  int t = threadIdx.x;
  int loc[8]; int s = 0;
  #pragma unroll
  for (int i=0;i<8;++i){ loc[i]=s; s += deg[t*8+i] + 1; }
  buf[t] = s; __syncthreads();
  for (int off=1; off<1024; off<<=1){
    int v = (t>=off) ? buf[t-off] : 0; __syncthreads();
    buf[t] += v; __syncthreads();
  }
  int base = buf[t] - s;
  #pragma unroll
  for (int i=0;i<8;++i) rowptr[t*8+i] = base + loc[i];
  if (t==1023) rowptr[8192] = buf[1023];
}

// CSR fill: csr_src + per-edge CSR position (posE), for edges AND self-loops
__global__ void k_fill(const int* __restrict__ ei, const int* __restrict__ rowptr,
                       int* __restrict__ fillpos, int* __restrict__ csr_src,
                       int* __restrict__ posE){
  int e = blockIdx.x*blockDim.x + threadIdx.x;
  if (e >= EP) return;
  int s, tg;
  if (e < N_EDGES){ s = ei[e]; tg = ei[N_EDGES+e]; }
  else            { s = tg = e - N_EDGES; }
  int pos = rowptr[tg] + atomicAdd(&fillpos[tg], 1);
  csr_src[pos] = s; posE[e] = pos;
}

// edge attr encode -> ea_pk (CSR order, bf16x2 packed: 11 data uints + 1 pad)
__global__ void k_encode_edges(const float* __restrict__ edge_attr, const float* __restrict__ bond_emb,
                               const float* __restrict__ bool_emb, const int* __restrict__ posE,
                               unsigned* __restrict__ ea_pk){
  int e = blockIdx.x*blockDim.x + threadIdx.x;
  if (e >= N_EDGES) return;
  float a0 = edge_attr[e*4+0], a1 = edge_attr[e*4+1];
  float a2 = edge_attr[e*4+2], a3 = edge_attr[e*4+3];
  int bi = (int)a0, b2 = (int)a2, b3 = (int)a3;
  int pos = posE[e];
  float v[22];
  #pragma unroll
  for (int j=0;j<16;++j) v[j] = bond_emb[bi*16+j];
  v[16] = a1;
  v[17] = bool_emb[b2*2+0]; v[18] = bool_emb[b2*2+1];
  v[19] = bool_emb[b3*2+0]; v[20] = bool_emb[b3*2+1];
  v[21] = 0.f;
  #pragma unroll
  for (int j=0;j<11;++j) ea_pk[(size_t)pos*12 + j] = pk2(v[2*j], v[2*j+1]);
  ea_pk[(size_t)pos*12 + 11] = 0u;
}

// loopsum accumulation (f32 atomics, target-indexed)
__global__ void k_loopsum(const float* __restrict__ edge_attr, const float* __restrict__ bond_emb,
                          const float* __restrict__ bool_emb, const int* __restrict__ ei,
                          float* __restrict__ loopsum){
  int e = blockIdx.x*blockDim.x + threadIdx.x;
  if (e >= N_EDGES) return;
  float a0 = edge_attr[e*4+0], a1 = edge_attr[e*4+1];
  float a2 = edge_attr[e*4+2], a3 = edge_attr[e*4+3];
  int bi = (int)a0, b2 = (int)a2, b3 = (int)a3;
  int tg = ei[N_EDGES + e];
  float v[21];
  #pragma unroll
  for (int j=0;j<16;++j) v[j] = bond_emb[bi*16+j];
  v[16] = a1;
  v[17] = bool_emb[b2*2+0]; v[18] = bool_emb[b2*2+1];
  v[19] = bool_emb[b3*2+0]; v[20] = bool_emb[b3*2+1];
  #pragma unroll
  for (int j=0;j<21;++j) atomicAdd(&loopsum[tg*21+j], v[j]);
}

// self-loop attr = mean of incoming, packed at CSR position posE[N_EDGES+n]
__global__ void k_loop_attr(const float* __restrict__ loopsum, const int* __restrict__ deg,
                            const int* __restrict__ posE, unsigned* __restrict__ ea_pk){
  int n = blockIdx.x*blockDim.x + threadIdx.x;
  if (n >= N_NODES) return;
  float c = (float)deg[n]; if (c < 1.f) c = 1.f;
  float inv = 1.f / c;
  int pos = posE[N_EDGES + n];
  float v[22];
  #pragma unroll
  for (int j=0;j<21;++j) v[j] = loopsum[n*21+j] * inv;
  v[21] = 0.f;
  #pragma unroll
  for (int j=0;j<11;++j) ea_pk[(size_t)pos*12 + j] = pk2(v[2*j], v[2*j+1]);
  ea_pk[(size_t)pos*12 + 11] = 0u;
}

__global__ void k_goff(const int* __restrict__ batch, int* __restrict__ goff){
  int n = blockIdx.x*blockDim.x + threadIdx.x;
  if (n >= N_NODES) return;
  int b = batch[n];
  if (n == 0){ for (int g=0; g<=b; ++g) goff[g] = 0; }
  else { int bp = batch[n-1]; for (int g=bp+1; g<=b; ++g) goff[g] = n; }
  if (n == N_NODES-1){ for (int g=b+1; g<=N_GROUPS; ++g) goff[g] = N_NODES; }
}

// ---------------- split-precision prep ----------------
__global__ void k_splitA(const float* __restrict__ A, bf16_t* __restrict__ Ah,
                         bf16_t* __restrict__ Al, int K, int Kp){
  int idx = blockIdx.x*blockDim.x + threadIdx.x;
  if (idx >= N_NODES*Kp) return;
  int k = idx % Kp;
  int n = idx / Kp;
  float v = (k < K) ? A[(size_t)n*K + k] : 0.f;
  bf16_t hi = (bf16_t)v;
  bf16_t lo = (bf16_t)(v - (float)hi);
  Ah[idx] = hi; Al[idx] = lo;
}

__global__ void k_splitW(const float* __restrict__ W, bf16_t* __restrict__ Wh,
                         bf16_t* __restrict__ Wl, int K, int Kp, int Nc){
  int idx = blockIdx.x*blockDim.x + threadIdx.x;
  if (idx >= Nc*Kp) return;
  int k = idx % Kp;
  int n = idx / Kp;
  float v = (k < K) ? W[(size_t)k*Nc + n] : 0.f;
  bf16_t hi = (bf16_t)v;
  bf16_t lo = (bf16_t)(v - (float)hi);
  Wh[idx] = hi; Wl[idx] = lo;
}

// ---------------- split-bf16 MFMA GEMM (Ah@Wh + Al@Wh + Ah@Wl) ----------------
#define BM 128
#define BN 128
#define BK 64
__global__ __launch_bounds__(256) void k_gemm3_mfma(
    const bf16_t* __restrict__ Ah, const bf16_t* __restrict__ Al,
    const bf16_t* __restrict__ Wh, const bf16_t* __restrict__ Wl,
    const float* __restrict__ bias, float* __restrict__ C,
    int Kp, int Nc)
{
  __shared__ __align__(16) bf16_t sA[BM*BK];
  __shared__ __align__(16) bf16_t sB[BN*BK];
  int t = threadIdx.x;
  int lane = t & 63;
  int w = t >> 6;
  int wr = w >> 1, wc = w & 1;
  int bm = blockIdx.y * BM, bn = blockIdx.x * BN;

  f32x4 acc[4][4] = {};

  int srow = t >> 3;
  int scol = (t & 7) * 8;

  for (int seg = 0; seg < 3; ++seg){
    const bf16_t* As = (seg == 1) ? Al : Ah;
    const bf16_t* Bs = (seg == 2) ? Wl : Wh;
    for (int k0 = 0; k0 < Kp; k0 += BK){
      #pragma unroll
      for (int i = 0; i < 4; ++i){
        int row = srow + i*32;
        gload_lds16(As + (size_t)(bm + row)*Kp + k0 + scol, (char*)sA + (t + i*256)*16);
        gload_lds16(Bs + (size_t)(bn + row)*Kp + k0 + scol, (char*)sB + (t + i*256)*16);
      }
      __syncthreads();
      #pragma unroll
      for (int kk = 0; kk < BK; kk += 32){
        bf16x8 af[4], bfr[4];
        int ko = kk + (lane >> 4)*8;
        #pragma unroll
        for (int m=0;m<4;++m)
          af[m] = *(const bf16x8*)&sA[(wr*64 + m*16 + (lane&15))*BK + ko];
        #pragma unroll
        for (int n=0;n<4;++n)
          bfr[n] = *(const bf16x8*)&sB[(wc*64 + n*16 + (lane&15))*BK + ko];
        #pragma unroll
        for (int m=0;m<4;++m)
          #pragma unroll
          for (int n=0;n<4;++n)
            acc[m][n] = __builtin_amdgcn_mfma_f32_16x16x32_bf16(af[m], bfr[n], acc[m][n], 0, 0, 0);
      }
      __syncthreads();
    }
  }

  int r0 = bm + wr*64 + ((lane>>4)<<2);
  int c0 = bn + wc*64 + (lane&15);
  #pragma unroll
  for (int n=0;n<4;++n){
    float bv = bias[c0 + n*16];
    #pragma unroll
    for (int m=0;m<4;++m){
      #pragma unroll
      for (int j=0;j<4;++j)
        C[(size_t)(r0 + m*16 + j)*Nc + c0 + n*16] = acc[m][n][j] + bv;
    }
  }
}

// ---------------- fused edge phase: logits + softmax + aggregate ----------------
// one wave per target node; 4 nodes per 256-thread block; no __syncthreads.
// edge attrs held PACKED (bf16x2) in VGPRs across the whole channel loop.
__global__ __launch_bounds__(256, 4) void k_edge_fused(
    const float* __restrict__ XL, const float* __restrict__ XR,
    const unsigned* __restrict__ ea_pk, const float* __restrict__ We,
    const float* __restrict__ att, const float* __restrict__ bias,
    const int* __restrict__ rowptr, const int* __restrict__ csr_src,
    float* __restrict__ hout, int C)
{
  __shared__ float sAl[4][DEGCAP];
  __shared__ int   sSrc[4][DEGCAP];
  int t = threadIdx.x;
  int lane = t & 63, w = t >> 6;
  int n = blockIdx.x*4 + w;
  int p0 = rowptr[n];
  int deg = rowptr[n+1] - p0;
  if (deg > DEGCAP) deg = DEGCAP;   // P(deg>64) ~ 1e-38 for Poisson(9)

  if (lane < deg) sSrc[w][lane] = csr_src[p0 + lane];

  // ---- logits: groups of 4 edges; packed ea in VGPRs (44); We chunk in VGPRs ----
  float lreg = -1e30f;
  for (int g = 0; g < deg; g += EDGE_B){
    unsigned earr[EDGE_B][11];
    int   sidx[EDGE_B];
    #pragma unroll
    for (int i=0;i<EDGE_B;++i){
      int qq = (g+i < deg) ? (g+i) : 0;
      sidx[i] = sSrc[w][qq];
      const unsigned* ep = ea_pk + (size_t)(p0+qq)*12;
      #pragma unroll
      for (int j=0;j<11;++j) earr[i][j] = ep[j];
    }
    float acc[EDGE_B] = {0.f,0.f,0.f,0.f};
    for (int c0 = 0; c0 < C; c0 += 64){
      int c = c0 + lane;
      float wreg[22];
      #pragma unroll
      for (int j=0;j<21;++j) wreg[j] = We[(size_t)j*C + c];
      wreg[21] = 0.f;
      float xr = XR[(size_t)n*C + c];
      float av = att[c];
      #pragma unroll
      for (int i=0;i<EDGE_B;++i){
        if (g+i < deg){
          float m = XL[(size_t)sidx[i]*C + c] + xr;
          #pragma unroll
          for (int j=0;j<11;++j){
            unsigned u = earr[i][j];
            m += bf_lo(u)*wreg[2*j] + bf_hi(u)*wreg[2*j+1];
          }
          acc[i] += lrelu(m)*av;
        }
      }
    }
    #pragma unroll
    for (int i=0;i<EDGE_B;++i){
      if (g+i < deg){
        float v = acc[i];
        #pragma unroll
        for (int off=32; off; off>>=1) v += __shfl_xor(v, off);
        if (lane == g+i) lreg = v;   // logit of edge q lives in lane q
      }
    }
  }

  // ---- in-wave softmax over lanes [0,deg) ----
  float mx = lreg;
  #pragma unroll
  for (int off=32; off; off>>=1) mx = fmaxf(mx, __shfl_xor(mx, off));
  float ex = (lane < deg) ? __expf(lreg - mx) : 0.f;
  float sm = ex;
  #pragma unroll
  for (int off=32; off; off>>=1) sm += __shfl_xor(sm, off);
  sAl[w][lane] = ex / sm;

  // ---- aggregation: hout[n] = relu(sum alpha*XL[src] + b), float4 lanes ----
  for (int c0 = 4*lane; c0 < C; c0 += 256){
    f32x4 a4 = *(const f32x4*)&bias[c0];
    for (int p = 0; p < deg; ++p){
      float al = sAl[w][p];
      int s = sSrc[w][p];
      f32x4 v4 = *(const f32x4*)&XL[(size_t)s*C + c0];
      a4 += al * v4;
    }
    f32x4 r;
    #pragma unroll
    for (int j=0;j<4;++j) r[j] = fmaxf(a4[j], 0.f);
    *(f32x4*)&hout[(size_t)n*C + c0] = r;
  }
}

// ---------------- graph mean pool (C=512) ----------------
__global__ void k_pool(const float* __restrict__ h, const int* __restrict__ goff,
                       float* __restrict__ out){
  int g = blockIdx.x >> 1;
  int c = ((blockIdx.x & 1) * 256) + threadIdx.x;
  int n0 = goff[g], n1 = goff[g+1];
  float s = 0.f;
  for (int n=n0;n<n1;++n) s += h[(size_t)n*512 + c];
  float cf = (float)(n1-n0); if (cf < 1.f) cf = 1.f;
  out[g*512 + c] = s / cf;
}

extern "C" void kernel_launch(void* const* d_in, const int* in_sizes, int n_in,
                              void* d_out, int out_size, void* d_ws, size_t ws_size,
                              hipStream_t stream) {
  (void)in_sizes; (void)n_in; (void)out_size; (void)ws_size;
  const float* x         = (const float*)d_in[0];
  const float* edge_attr = (const float*)d_in[1];
  const float* atom_emb  = (const float*)d_in[2];
  const float* bond_emb  = (const float*)d_in[3];
  const float* bool_emb  = (const float*)d_in[4];
  const int*   ei        = (const int*)d_in[5];
  const int*   batch     = (const int*)d_in[6];

  struct Layer { const float *Wl,*bl,*Wr,*br,*We,*att,*b; int Cin,Cout,Kp; };
  const int dims[5] = {74, 2048, 1024, 512, 512};
  const int kpad[4] = {128, 2048, 1024, 512};
  Layer L[4];
  for (int i=0;i<4;++i){
    const int o = 7 + i*7;
    L[i] = { (const float*)d_in[o+0], (const float*)d_in[o+1], (const float*)d_in[o+2],
             (const float*)d_in[o+3], (const float*)d_in[o+4], (const float*)d_in[o+5],
             (const float*)d_in[o+6], dims[i], dims[i+1], kpad[i] };
  }

  char* ws = (char*)d_ws;
  size_t off = 0;
  auto alloc = [&](size_t bytes)->void*{ void* p = ws + off; off += (bytes + 255) & ~(size_t)255; return p; };
  float* slot[3];
  slot[0] = (float*)alloc((size_t)N_NODES*1024*4);
  slot[1] = (float*)alloc((size_t)N_NODES*2048*4);
  slot[2] = (float*)alloc((size_t)N_NODES*2048*4);
  bf16_t* Ahb = (bf16_t*)alloc((size_t)N_NODES*2048*2);
  bf16_t* Alb = (bf16_t*)alloc((size_t)N_NODES*2048*2);
  bf16_t* Whb = (bf16_t*)alloc((size_t)1024*2048*2);
  bf16_t* Wlb = (bf16_t*)alloc((size_t)1024*2048*2);
  unsigned* ea_pk = (unsigned*)alloc((size_t)EP*12*4);
  float* loopsum = (float*)alloc((size_t)N_NODES*21*4);
  int*   deg     = (int*)alloc((size_t)N_NODES*4);
  int*   rowptr  = (int*)alloc((size_t)(N_NODES+1)*4);
  int*   fillpos = (int*)alloc((size_t)N_NODES*4);
  int*   csr_src = (int*)alloc((size_t)EP*4);
  int*   posE    = (int*)alloc((size_t)EP*4);
  int*   goff    = (int*)alloc((size_t)(N_GROUPS+1)*4);

  hipMemsetAsync(loopsum, 0, (size_t)N_NODES*21*4, stream);
  hipMemsetAsync(deg,     0, (size_t)N_NODES*4, stream);
  hipMemsetAsync(fillpos, 0, (size_t)N_NODES*4, stream);

  // structure + encoding (ea built packed, directly in CSR order)
  k_encode_nodes<<<(N_NODES*74 + 255)/256, 256, 0, stream>>>(x, atom_emb, bool_emb, slot[0]);
  k_deg<<<N_EDGES/256, 256, 0, stream>>>(ei, deg);
  k_scan<<<1, 1024, 0, stream>>>(deg, rowptr);
  k_fill<<<(EP + 255)/256, 256, 0, stream>>>(ei, rowptr, fillpos, csr_src, posE);
  k_encode_edges<<<N_EDGES/256, 256, 0, stream>>>(edge_attr, bond_emb, bool_emb, posE, ea_pk);
  k_loopsum<<<N_EDGES/256, 256, 0, stream>>>(edge_attr, bond_emb, bool_emb, ei, loopsum);
  k_loop_attr<<<(N_NODES + 255)/256, 256, 0, stream>>>(loopsum, deg, posE, ea_pk);
  k_goff<<<N_NODES/256, 256, 0, stream>>>(batch, goff);

  // 4 GATv2 layers
  int hIdx = 0;
  for (int li=0; li<4; ++li){
    int xlIdx = (hIdx+1)%3, xrIdx = (hIdx+2)%3;
    float* h  = slot[hIdx];
    float* XL = slot[xlIdx];
    float* XR = slot[xrIdx];
    int K = L[li].Cin, C = L[li].Cout, Kp = L[li].Kp;
    dim3 ggrid(C/BN, N_NODES/BM);

    k_splitA<<<((size_t)N_NODES*Kp + 255)/256, 256, 0, stream>>>(h, Ahb, Alb, K, Kp);

    k_splitW<<<((size_t)C*Kp + 255)/256, 256, 0, stream>>>(L[li].Wl, Whb, Wlb, K, Kp, C);
    k_gemm3_mfma<<<ggrid, 256, 0, stream>>>(Ahb, Alb, Whb, Wlb, L[li].bl, XL, Kp, C);

    k_splitW<<<((size_t)C*Kp + 255)/256, 256, 0, stream>>>(L[li].Wr, Whb, Wlb, K, Kp, C);
    k_gemm3_mfma<<<ggrid, 256, 0, stream>>>(Ahb, Alb, Whb, Wlb, L[li].br, XR, Kp, C);

    k_edge_fused<<<N_NODES/4, 256, 0, stream>>>(XL, XR, ea_pk, L[li].We, L[li].att,
                                                L[li].b, rowptr, csr_src, XR, C);
    hIdx = xrIdx;
  }

  k_pool<<<N_GROUPS*2, 256, 0, stream>>>(slot[hIdx], goff, (float*)d_out);
}

// Round 5
// 1871.813 us; speedup vs baseline: 1.3239x; 1.3239x over previous
//
#include <hip/hip_runtime.h>
#include <hip/hip_bf16.h>

#define N_NODES 8192
#define N_EDGES 65536
#define EP (N_EDGES + N_NODES)   // 73728 edges incl self-loops
#define N_GROUPS 64
#define DEGCAP 64
#define EDGE_B 4

typedef __bf16 bf16_t;
typedef bf16_t bf16x8 __attribute__((ext_vector_type(8)));
typedef float  f32x4  __attribute__((ext_vector_type(4)));

__device__ __forceinline__ float lrelu(float v){ return v > 0.f ? v : 0.2f*v; }

__device__ __forceinline__ void gload_lds16(const void* g, void* l){
  typedef __attribute__((address_space(1))) const void gvoid_t;
  typedef __attribute__((address_space(3))) void lvoid_t;
  __builtin_amdgcn_global_load_lds((gvoid_t*)g, (lvoid_t*)l, 16, 0, 0);
}

// bf16-pair pack/unpack (lo -> low 16 bits, hi -> high 16 bits)
__device__ __forceinline__ unsigned pk2(float a, float b){
  __hip_bfloat16 ha = __float2bfloat16(a), hb = __float2bfloat16(b);
  unsigned short ua = *(unsigned short*)&ha, ub = *(unsigned short*)&hb;
  return (unsigned)ua | ((unsigned)ub << 16);
}
__device__ __forceinline__ float bf_lo(unsigned u){ union{unsigned i;float f;}x; x.i = u << 16; return x.f; }
__device__ __forceinline__ float bf_hi(unsigned u){ union{unsigned i;float f;}x; x.i = u & 0xffff0000u; return x.f; }

// ---------------- feature encoding ----------------
__global__ void k_encode_nodes(const float* __restrict__ x, const float* __restrict__ atom_emb,
                               const float* __restrict__ bool_emb, float* __restrict__ h){
  int idx = blockIdx.x*blockDim.x + threadIdx.x;
  if (idx >= N_NODES*74) return;
  int n = idx / 74, c = idx % 74;
  float v;
  if (c < 64)      { int ai = (int)x[n*10+0]; v = atom_emb[ai*64 + c]; }
  else if (c < 72) { v = x[n*10 + 1 + (c-64)]; }
  else             { int bi = (int)x[n*10+9]; v = bool_emb[bi*2 + (c-72)]; }
  h[n*74 + c] = v;
}

// incoming-degree count (real edges only)
__global__ void k_deg(const int* __restrict__ ei, int* __restrict__ deg){
  int e = blockIdx.x*blockDim.x + threadIdx.x;
  if (e >= N_EDGES) return;
  atomicAdd(&deg[ei[N_EDGES + e]], 1);
}

// exclusive scan of (deg[i]+1) over 8192 entries -> rowptr (self-loop slot included)
__global__ __launch_bounds__(1024) void k_scan(const int* __restrict__ deg, int* __restrict__ rowptr){
  __shared__ int buf[1024];
  int t = threadIdx.x;
  int loc[8]; int s = 0;
  #pragma unroll
  for (int i=0;i<8;++i){ loc[i]=s; s += deg[t*8+i] + 1; }
  buf[t] = s; __syncthreads();
  for (int off=1; off<1024; off<<=1){
    int v = (t>=off) ? buf[t-off] : 0; __syncthreads();
    buf[t] += v; __syncthreads();
  }
  int base = buf[t] - s;
  #pragma unroll
  for (int i=0;i<8;++i) rowptr[t*8+i] = base + loc[i];
  if (t==1023) rowptr[8192] = buf[1023];
}

// CSR fill: csr_src + per-edge CSR position (posE), for edges AND self-loops
__global__ void k_fill(const int* __restrict__ ei, const int* __restrict__ rowptr,
                       int* __restrict__ fillpos, int* __restrict__ csr_src,
                       int* __restrict__ posE){
  int e = blockIdx.x*blockDim.x + threadIdx.x;
  if (e >= EP) return;
  int s, tg;
  if (e < N_EDGES){ s = ei[e]; tg = ei[N_EDGES+e]; }
  else            { s = tg = e - N_EDGES; }
  int pos = rowptr[tg] + atomicAdd(&fillpos[tg], 1);
  csr_src[pos] = s; posE[e] = pos;
}

// edge attr encode -> ea_pk (CSR order, bf16x2 packed: 11 data uints + 1 pad)
__global__ void k_encode_edges(const float* __restrict__ edge_attr, const float* __restrict__ bond_emb,
                               const float* __restrict__ bool_emb, const int* __restrict__ posE,
                               unsigned* __restrict__ ea_pk){
  int e = blockIdx.x*blockDim.x + threadIdx.x;
  if (e >= N_EDGES) return;
  float a0 = edge_attr[e*4+0], a1 = edge_attr[e*4+1];
  float a2 = edge_attr[e*4+2], a3 = edge_attr[e*4+3];
  int bi = (int)a0, b2 = (int)a2, b3 = (int)a3;
  int pos = posE[e];
  float v[22];
  #pragma unroll
  for (int j=0;j<16;++j) v[j] = bond_emb[bi*16+j];
  v[16] = a1;
  v[17] = bool_emb[b2*2+0]; v[18] = bool_emb[b2*2+1];
  v[19] = bool_emb[b3*2+0]; v[20] = bool_emb[b3*2+1];
  v[21] = 0.f;
  #pragma unroll
  for (int j=0;j<11;++j) ea_pk[(size_t)pos*12 + j] = pk2(v[2*j], v[2*j+1]);
  ea_pk[(size_t)pos*12 + 11] = 0u;
}

// loopsum accumulation (f32 atomics, target-indexed)
__global__ void k_loopsum(const float* __restrict__ edge_attr, const float* __restrict__ bond_emb,
                          const float* __restrict__ bool_emb, const int* __restrict__ ei,
                          float* __restrict__ loopsum){
  int e = blockIdx.x*blockDim.x + threadIdx.x;
  if (e >= N_EDGES) return;
  float a0 = edge_attr[e*4+0], a1 = edge_attr[e*4+1];
  float a2 = edge_attr[e*4+2], a3 = edge_attr[e*4+3];
  int bi = (int)a0, b2 = (int)a2, b3 = (int)a3;
  int tg = ei[N_EDGES + e];
  float v[21];
  #pragma unroll
  for (int j=0;j<16;++j) v[j] = bond_emb[bi*16+j];
  v[16] = a1;
  v[17] = bool_emb[b2*2+0]; v[18] = bool_emb[b2*2+1];
  v[19] = bool_emb[b3*2+0]; v[20] = bool_emb[b3*2+1];
  #pragma unroll
  for (int j=0;j<21;++j) atomicAdd(&loopsum[tg*21+j], v[j]);
}

// self-loop attr = mean of incoming, packed at CSR position posE[N_EDGES+n]
__global__ void k_loop_attr(const float* __restrict__ loopsum, const int* __restrict__ deg,
                            const int* __restrict__ posE, unsigned* __restrict__ ea_pk){
  int n = blockIdx.x*blockDim.x + threadIdx.x;
  if (n >= N_NODES) return;
  float c = (float)deg[n]; if (c < 1.f) c = 1.f;
  float inv = 1.f / c;
  int pos = posE[N_EDGES + n];
  float v[22];
  #pragma unroll
  for (int j=0;j<21;++j) v[j] = loopsum[n*21+j] * inv;
  v[21] = 0.f;
  #pragma unroll
  for (int j=0;j<11;++j) ea_pk[(size_t)pos*12 + j] = pk2(v[2*j], v[2*j+1]);
  ea_pk[(size_t)pos*12 + 11] = 0u;
}

__global__ void k_goff(const int* __restrict__ batch, int* __restrict__ goff){
  int n = blockIdx.x*blockDim.x + threadIdx.x;
  if (n >= N_NODES) return;
  int b = batch[n];
  if (n == 0){ for (int g=0; g<=b; ++g) goff[g] = 0; }
  else { int bp = batch[n-1]; for (int g=bp+1; g<=b; ++g) goff[g] = n; }
  if (n == N_NODES-1){ for (int g=b+1; g<=N_GROUPS; ++g) goff[g] = N_NODES; }
}

// ---------------- split-precision prep ----------------
__global__ void k_splitA(const float* __restrict__ A, bf16_t* __restrict__ Ah,
                         bf16_t* __restrict__ Al, int K, int Kp){
  int idx = blockIdx.x*blockDim.x + threadIdx.x;
  if (idx >= N_NODES*Kp) return;
  int k = idx % Kp;
  int n = idx / Kp;
  float v = (k < K) ? A[(size_t)n*K + k] : 0.f;
  bf16_t hi = (bf16_t)v;
  bf16_t lo = (bf16_t)(v - (float)hi);
  Ah[idx] = hi; Al[idx] = lo;
}

__global__ void k_splitW(const float* __restrict__ W, bf16_t* __restrict__ Wh,
                         bf16_t* __restrict__ Wl, int K, int Kp, int Nc){
  int idx = blockIdx.x*blockDim.x + threadIdx.x;
  if (idx >= Nc*Kp) return;
  int k = idx % Kp;
  int n = idx / Kp;
  float v = (k < K) ? W[(size_t)k*Nc + n] : 0.f;
  bf16_t hi = (bf16_t)v;
  bf16_t lo = (bf16_t)(v - (float)hi);
  Wh[idx] = hi; Wl[idx] = lo;
}

// ---------------- split-bf16 MFMA GEMM (Ah@Wh + Al@Wh + Ah@Wl) ----------------
#define BM 128
#define BN 128
#define BK 64
__global__ __launch_bounds__(256) void k_gemm3_mfma(
    const bf16_t* __restrict__ Ah, const bf16_t* __restrict__ Al,
    const bf16_t* __restrict__ Wh, const bf16_t* __restrict__ Wl,
    const float* __restrict__ bias, float* __restrict__ C,
    int Kp, int Nc)
{
  __shared__ __align__(16) bf16_t sA[BM*BK];
  __shared__ __align__(16) bf16_t sB[BN*BK];
  int t = threadIdx.x;
  int lane = t & 63;
  int w = t >> 6;
  int wr = w >> 1, wc = w & 1;
  int bm = blockIdx.y * BM, bn = blockIdx.x * BN;

  f32x4 acc[4][4] = {};

  int srow = t >> 3;
  int scol = (t & 7) * 8;

  for (int seg = 0; seg < 3; ++seg){
    const bf16_t* As = (seg == 1) ? Al : Ah;
    const bf16_t* Bs = (seg == 2) ? Wl : Wh;
    for (int k0 = 0; k0 < Kp; k0 += BK){
      #pragma unroll
      for (int i = 0; i < 4; ++i){
        int row = srow + i*32;
        gload_lds16(As + (size_t)(bm + row)*Kp + k0 + scol, (char*)sA + (t + i*256)*16);
        gload_lds16(Bs + (size_t)(bn + row)*Kp + k0 + scol, (char*)sB + (t + i*256)*16);
      }
      __syncthreads();
      #pragma unroll
      for (int kk = 0; kk < BK; kk += 32){
        bf16x8 af[4], bfr[4];
        int ko = kk + (lane >> 4)*8;
        #pragma unroll
        for (int m=0;m<4;++m)
          af[m] = *(const bf16x8*)&sA[(wr*64 + m*16 + (lane&15))*BK + ko];
        #pragma unroll
        for (int n=0;n<4;++n)
          bfr[n] = *(const bf16x8*)&sB[(wc*64 + n*16 + (lane&15))*BK + ko];
        #pragma unroll
        for (int m=0;m<4;++m)
          #pragma unroll
          for (int n=0;n<4;++n)
            acc[m][n] = __builtin_amdgcn_mfma_f32_16x16x32_bf16(af[m], bfr[n], acc[m][n], 0, 0, 0);
      }
      __syncthreads();
    }
  }

  int r0 = bm + wr*64 + ((lane>>4)<<2);
  int c0 = bn + wc*64 + (lane&15);
  #pragma unroll
  for (int n=0;n<4;++n){
    float bv = bias[c0 + n*16];
    #pragma unroll
    for (int m=0;m<4;++m){
      #pragma unroll
      for (int j=0;j<4;++j)
        C[(size_t)(r0 + m*16 + j)*Nc + c0 + n*16] = acc[m][n][j] + bv;
    }
  }
}

// ---------------- fused edge phase: logits + softmax + aggregate ----------------
// 2 waves per node (channel-split), 2 nodes per 256-thread block.
// edge attrs: packed bf16x2, loaded from global via wave-uniform base (scalarizable).
__global__ __launch_bounds__(256) void k_edge_fused(
    const float* __restrict__ XL, const float* __restrict__ XR,
    const unsigned* __restrict__ ea_pk, const float* __restrict__ We,
    const float* __restrict__ att, const float* __restrict__ bias,
    const int* __restrict__ rowptr, const int* __restrict__ csr_src,
    float* __restrict__ hout, int C)
{
  __shared__ float sPart[2][DEGCAP];
  __shared__ float sAl[2][DEGCAP];
  __shared__ int   sSrc[2][DEGCAP];
  int t = threadIdx.x;
  int lane = t & 63, w = t >> 6;
  int u = w >> 1, half = w & 1;       // u: which node of the block; half: channel half
  int n = blockIdx.x*2 + u;
  int p0 = rowptr[n];
  int deg = rowptr[n+1] - p0;
  if (deg > DEGCAP) deg = DEGCAP;     // P(deg>64) ~ 1e-38 for Poisson(9)
  int p0s = __builtin_amdgcn_readfirstlane(p0);

  if (half == 0 && lane < deg) sSrc[u][lane] = csr_src[p0 + lane];
  __syncthreads();

  // ---- logit partials over this wave's channel half (c = half*64 + k*128 + lane) ----
  float lpart = 0.f;   // partial logit of edge 'lane' (valid for lane < deg)
  for (int g = 0; g < deg; g += EDGE_B){
    unsigned earr[EDGE_B][11];
    int sidx[EDGE_B];
    #pragma unroll
    for (int i=0;i<EDGE_B;++i){
      int qq = (g+i < deg) ? (g+i) : 0;
      sidx[i] = sSrc[u][qq];
      const unsigned* ep = ea_pk + (size_t)(p0s+qq)*12;
      #pragma unroll
      for (int j=0;j<11;++j) earr[i][j] = ep[j];
    }
    float acc[EDGE_B] = {0.f,0.f,0.f,0.f};
    for (int c0 = half*64; c0 < C; c0 += 128){
      int c = c0 + lane;
      float wreg[21];
      #pragma unroll
      for (int j=0;j<21;++j) wreg[j] = We[(size_t)j*C + c];
      float xr = XR[(size_t)n*C + c];
      float av = att[c];
      #pragma unroll
      for (int i=0;i<EDGE_B;++i){
        if (g+i < deg){
          float m = XL[(size_t)sidx[i]*C + c] + xr;
          #pragma unroll
          for (int j=0;j<10;++j){
            unsigned uu = earr[i][j];
            m += bf_lo(uu)*wreg[2*j] + bf_hi(uu)*wreg[2*j+1];
          }
          m += bf_lo(earr[i][10])*wreg[20];
          acc[i] += lrelu(m)*av;
        }
      }
    }
    #pragma unroll
    for (int i=0;i<EDGE_B;++i){
      if (g+i < deg){
        float v = acc[i];
        #pragma unroll
        for (int off=32; off; off>>=1) v += __shfl_xor(v, off);
        if (lane == g+i) lpart = v;
      }
    }
  }

  // ---- combine the two halves' partials; softmax on half==1 wave ----
  if (half == 0) sPart[u][lane] = lpart;
  __syncthreads();
  if (half == 1){
    float tot = (lane < deg) ? (lpart + sPart[u][lane]) : -1e30f;
    float mx = tot;
    #pragma unroll
    for (int off=32; off; off>>=1) mx = fmaxf(mx, __shfl_xor(mx, off));
    float ex = (lane < deg) ? __expf(tot - mx) : 0.f;
    float sm = ex;
    #pragma unroll
    for (int off=32; off; off>>=1) sm += __shfl_xor(sm, off);
    sAl[u][lane] = ex / sm;
  }
  __syncthreads();

  // ---- aggregation: this wave covers channels [half*C/2, (half+1)*C/2) ----
  int cbase = half*(C>>1), cend = cbase + (C>>1);
  for (int c0 = cbase + 4*lane; c0 < cend; c0 += 256){
    f32x4 a4 = *(const f32x4*)&bias[c0];
    for (int p = 0; p < deg; ++p){
      float al = sAl[u][p];
      int s = sSrc[u][p];
      f32x4 v4 = *(const f32x4*)&XL[(size_t)s*C + c0];
      a4 += al * v4;
    }
    f32x4 r;
    #pragma unroll
    for (int j=0;j<4;++j) r[j] = fmaxf(a4[j], 0.f);
    *(f32x4*)&hout[(size_t)n*C + c0] = r;
  }
}

// ---------------- graph mean pool (C=512) ----------------
__global__ void k_pool(const float* __restrict__ h, const int* __restrict__ goff,
                       float* __restrict__ out){
  int g = blockIdx.x >> 1;
  int c = ((blockIdx.x & 1) * 256) + threadIdx.x;
  int n0 = goff[g], n1 = goff[g+1];
  float s = 0.f;
  for (int n=n0;n<n1;++n) s += h[(size_t)n*512 + c];
  float cf = (float)(n1-n0); if (cf < 1.f) cf = 1.f;
  out[g*512 + c] = s / cf;
}

extern "C" void kernel_launch(void* const* d_in, const int* in_sizes, int n_in,
                              void* d_out, int out_size, void* d_ws, size_t ws_size,
                              hipStream_t stream) {
  (void)in_sizes; (void)n_in; (void)out_size; (void)ws_size;
  const float* x         = (const float*)d_in[0];
  const float* edge_attr = (const float*)d_in[1];
  const float* atom_emb  = (const float*)d_in[2];
  const float* bond_emb  = (const float*)d_in[3];
  const float* bool_emb  = (const float*)d_in[4];
  const int*   ei        = (const int*)d_in[5];
  const int*   batch     = (const int*)d_in[6];

  struct Layer { const float *Wl,*bl,*Wr,*br,*We,*att,*b; int Cin,Cout,Kp; };
  const int dims[5] = {74, 2048, 1024, 512, 512};
  const int kpad[4] = {128, 2048, 1024, 512};
  Layer L[4];
  for (int i=0;i<4;++i){
    const int o = 7 + i*7;
    L[i] = { (const float*)d_in[o+0], (const float*)d_in[o+1], (const float*)d_in[o+2],
             (const float*)d_in[o+3], (const float*)d_in[o+4], (const float*)d_in[o+5],
             (const float*)d_in[o+6], dims[i], dims[i+1], kpad[i] };
  }

  char* ws = (char*)d_ws;
  size_t off = 0;
  auto alloc = [&](size_t bytes)->void*{ void* p = ws + off; off += (bytes + 255) & ~(size_t)255; return p; };
  float* slot[3];
  slot[0] = (float*)alloc((size_t)N_NODES*1024*4);
  slot[1] = (float*)alloc((size_t)N_NODES*2048*4);
  slot[2] = (float*)alloc((size_t)N_NODES*2048*4);
  bf16_t* Ahb = (bf16_t*)alloc((size_t)N_NODES*2048*2);
  bf16_t* Alb = (bf16_t*)alloc((size_t)N_NODES*2048*2);
  bf16_t* Whb = (bf16_t*)alloc((size_t)1024*2048*2);
  bf16_t* Wlb = (bf16_t*)alloc((size_t)1024*2048*2);
  unsigned* ea_pk = (unsigned*)alloc((size_t)EP*12*4);
  float* loopsum = (float*)alloc((size_t)N_NODES*21*4);
  int*   deg     = (int*)alloc((size_t)N_NODES*4);
  int*   rowptr  = (int*)alloc((size_t)(N_NODES+1)*4);
  int*   fillpos = (int*)alloc((size_t)N_NODES*4);
  int*   csr_src = (int*)alloc((size_t)EP*4);
  int*   posE    = (int*)alloc((size_t)EP*4);
  int*   goff    = (int*)alloc((size_t)(N_GROUPS+1)*4);

  hipMemsetAsync(loopsum, 0, (size_t)N_NODES*21*4, stream);
  hipMemsetAsync(deg,     0, (size_t)N_NODES*4, stream);
  hipMemsetAsync(fillpos, 0, (size_t)N_NODES*4, stream);

  // structure + encoding (ea built packed, directly in CSR order)
  k_encode_nodes<<<(N_NODES*74 + 255)/256, 256, 0, stream>>>(x, atom_emb, bool_emb, slot[0]);
  k_deg<<<N_EDGES/256, 256, 0, stream>>>(ei, deg);
  k_scan<<<1, 1024, 0, stream>>>(deg, rowptr);
  k_fill<<<(EP + 255)/256, 256, 0, stream>>>(ei, rowptr, fillpos, csr_src, posE);
  k_encode_edges<<<N_EDGES/256, 256, 0, stream>>>(edge_attr, bond_emb, bool_emb, posE, ea_pk);
  k_loopsum<<<N_EDGES/256, 256, 0, stream>>>(edge_attr, bond_emb, bool_emb, ei, loopsum);
  k_loop_attr<<<(N_NODES + 255)/256, 256, 0, stream>>>(loopsum, deg, posE, ea_pk);
  k_goff<<<N_NODES/256, 256, 0, stream>>>(batch, goff);

  // 4 GATv2 layers
  int hIdx = 0;
  for (int li=0; li<4; ++li){
    int xlIdx = (hIdx+1)%3, xrIdx = (hIdx+2)%3;
    float* h  = slot[hIdx];
    float* XL = slot[xlIdx];
    float* XR = slot[xrIdx];
    int K = L[li].Cin, C = L[li].Cout, Kp = L[li].Kp;
    dim3 ggrid(C/BN, N_NODES/BM);

    k_splitA<<<((size_t)N_NODES*Kp + 255)/256, 256, 0, stream>>>(h, Ahb, Alb, K, Kp);

    k_splitW<<<((size_t)C*Kp + 255)/256, 256, 0, stream>>>(L[li].Wl, Whb, Wlb, K, Kp, C);
    k_gemm3_mfma<<<ggrid, 256, 0, stream>>>(Ahb, Alb, Whb, Wlb, L[li].bl, XL, Kp, C);

    k_splitW<<<((size_t)C*Kp + 255)/256, 256, 0, stream>>>(L[li].Wr, Whb, Wlb, K, Kp, C);
    k_gemm3_mfma<<<ggrid, 256, 0, stream>>>(Ahb, Alb, Whb, Wlb, L[li].br, XR, Kp, C);

    k_edge_fused<<<N_NODES/2, 256, 0, stream>>>(XL, XR, ea_pk, L[li].We, L[li].att,
                                                L[li].b, rowptr, csr_src, XR, C);
    hIdx = xrIdx;
  }

  k_pool<<<N_GROUPS*2, 256, 0, stream>>>(slot[hIdx], goff, (float*)d_out);
}